// Round 1
// baseline (1258.761 us; speedup 1.0000x reference)
//
#include <hip/hip_runtime.h>
#include <hip/hip_bf16.h>
#include <math.h>

#define BB 4
#define CC 128
#define HH 128
#define WW 128
#define HWs 16384
#define GG 8
#define CGc 16
#define OMCH 216

// ---------------- prep: weight rearrange ----------------
// Wt_off[c][o]          (256 x 128)
// Wr_om[(c*9+tap)][o]   (1152 x 256, zero-padded o>=216)
// Wr_dcn[(c*9+k)][o]    (1152 x 128)
__global__ __launch_bounds__(256) void k_prep(const float* __restrict__ W_off,
                                              const float* __restrict__ W_om,
                                              const float* __restrict__ W_dcn,
                                              float* __restrict__ wt_off,
                                              float* __restrict__ wr_om,
                                              float* __restrict__ wr_dcn) {
    int idx = blockIdx.x * 256 + threadIdx.x;
    if (idx < 32768) {
        int c = idx >> 7, o = idx & 127;
        wt_off[idx] = W_off[o * 256 + c];
    } else if (idx < 32768 + 294912) {
        int j = idx - 32768;
        int o = j & 255;
        int ct = j >> 8;            // c*9+tap, 0..1151
        int c = ct / 9, tap = ct % 9;
        wr_om[j] = (o < OMCH) ? W_om[(o * 128 + c) * 9 + tap] : 0.0f;
    } else if (idx < 32768 + 294912 + 147456) {
        int j = idx - 327680;
        int o = j & 127;
        int ck = j >> 7;            // c*9+k
        int c = ck / 9, k = ck % 9;
        wr_dcn[j] = W_dcn[(o * 128 + c) * 9 + k];
    }
}

// ---------------- bilinear 2x upsample ----------------
__global__ __launch_bounds__(256) void k_upsample(const float* __restrict__ fs,
                                                  float* __restrict__ fu) {
    int idx = blockIdx.x * 256 + threadIdx.x;   // over B*C*H*W (exact)
    int x = idx & 127, y = (idx >> 7) & 127, bc = idx >> 14;
    int j = y >> 1, i = x >> 1;
    int ya, yb; float wya, wyb;
    if (y & 1) { ya = j; yb = (j < 63) ? j + 1 : 63; wya = 0.75f; wyb = 0.25f; }
    else       { ya = (j > 0) ? j - 1 : 0; yb = j;   wya = 0.25f; wyb = 0.75f; }
    int xa, xb; float wxa, wxb;
    if (x & 1) { xa = i; xb = (i < 63) ? i + 1 : 63; wxa = 0.75f; wxb = 0.25f; }
    else       { xa = (i > 0) ? i - 1 : 0; xb = i;   wxa = 0.25f; wxb = 0.75f; }
    const float* p = fs + (size_t)bc * 4096;
    float v = wya * (wxa * p[ya * 64 + xa] + wxb * p[ya * 64 + xb])
            + wyb * (wxa * p[yb * 64 + xa] + wxb * p[yb * 64 + xb]);
    fu[idx] = v;
}

// ---------------- 1x1 conv: offset_feat = W_off * concat(feat_l, 2*feat_up) ----------------
#define XLD1 68
__global__ __launch_bounds__(256) void k_conv1(const float* __restrict__ fl,
                                               const float* __restrict__ fu,
                                               const float* __restrict__ wt,
                                               float* __restrict__ outp) {
    __shared__ float Xl[128][XLD1];
    int t = threadIdx.x;
    int b = blockIdx.x >> 8;
    int pos0 = (blockIdx.x & 255) << 6;
    int og = t & 15, pg = t >> 4;
    float acc[8][4] = {};
    for (int c0 = 0; c0 < 256; c0 += 128) {
        __syncthreads();
        int p = t & 63, cb = t >> 6;
        #pragma unroll
        for (int r = 0; r < 32; ++r) {
            int c = c0 + cb + r * 4;
            float v;
            if (c < 128) v = fl[(size_t)(b * 128 + c) * HWs + pos0 + p];
            else         v = 2.0f * fu[(size_t)(b * 128 + (c - 128)) * HWs + pos0 + p];
            Xl[cb + r * 4][p] = v;
        }
        __syncthreads();
        #pragma unroll 4
        for (int cc = 0; cc < 128; ++cc) {
            const float4 xv = *(const float4*)&Xl[cc][pg * 4];
            const float* wr = wt + (size_t)(c0 + cc) * 128 + og * 8;
            const float4 wa = *(const float4*)wr;
            const float4 wb = *(const float4*)(wr + 4);
            float xs[4] = {xv.x, xv.y, xv.z, xv.w};
            float wv[8] = {wa.x, wa.y, wa.z, wa.w, wb.x, wb.y, wb.z, wb.w};
            #pragma unroll
            for (int jj = 0; jj < 8; ++jj)
                #pragma unroll
                for (int pp = 0; pp < 4; ++pp)
                    acc[jj][pp] = fmaf(wv[jj], xs[pp], acc[jj][pp]);
        }
    }
    #pragma unroll
    for (int jj = 0; jj < 8; ++jj) {
        int o = og * 8 + jj;
        float4 st = make_float4(acc[jj][0], acc[jj][1], acc[jj][2], acc[jj][3]);
        *(float4*)&outp[(size_t)(b * 128 + o) * HWs + pos0 + pg * 4] = st;
    }
}

// ---------------- 3x3 conv: om = conv(offset_feat, W_om) + b_om; sigmoid on ch>=144 ----------------
#define XLD3 68
__global__ __launch_bounds__(256) void k_conv3(const float* __restrict__ A,
                                               const float* __restrict__ wrom,
                                               const float* __restrict__ bom,
                                               float* __restrict__ om) {
    __shared__ float Xl[16][3][XLD3];
    int t = threadIdx.x;
    int b = blockIdx.x >> 8;
    int pos0 = (blockIdx.x & 255) << 6;
    int y = pos0 >> 7, x0 = pos0 & 127;
    int obase = blockIdx.y * 128;
    int og = t & 15, pg = t >> 4;
    float acc[8][4] = {};
    for (int c0 = 0; c0 < 128; c0 += 16) {
        __syncthreads();
        // stage 16 channels x 3 rows x 66 cols (zero-padded)
        for (int r = 0; r < 13; ++r) {
            int idx = t + r * 256;
            if (idx < 16 * 3 * 66) {
                int row = idx / 66, col = idx % 66;
                int cc = row / 3, dy = row % 3;
                int gy = y - 1 + dy;
                int gx = x0 - 1 + col;
                float v = 0.0f;
                if ((unsigned)gy < 128u && (unsigned)gx < 128u)
                    v = A[((size_t)(b * 128 + c0 + cc) * 128 + gy) * 128 + gx];
                Xl[cc][dy][col] = v;
            }
        }
        __syncthreads();
        for (int cc = 0; cc < 16; ++cc) {
            float row[3][6];
            #pragma unroll
            for (int dy = 0; dy < 3; ++dy)
                #pragma unroll
                for (int q = 0; q < 6; ++q)
                    row[dy][q] = Xl[cc][dy][pg * 4 + q];
            #pragma unroll
            for (int tap = 0; tap < 9; ++tap) {
                const int ky = tap / 3, kx = tap % 3;
                const float* wr = wrom + (size_t)((c0 + cc) * 9 + tap) * 256 + obase + og * 8;
                const float4 wa = *(const float4*)wr;
                const float4 wb = *(const float4*)(wr + 4);
                float wv[8] = {wa.x, wa.y, wa.z, wa.w, wb.x, wb.y, wb.z, wb.w};
                #pragma unroll
                for (int jj = 0; jj < 8; ++jj)
                    #pragma unroll
                    for (int pp = 0; pp < 4; ++pp)
                        acc[jj][pp] = fmaf(wv[jj], row[ky][pp + kx], acc[jj][pp]);
            }
        }
    }
    #pragma unroll
    for (int jj = 0; jj < 8; ++jj) {
        int o = obase + og * 8 + jj;
        if (o < OMCH) {
            float bv = bom[o];
            float4 st;
            float v0 = acc[jj][0] + bv, v1 = acc[jj][1] + bv, v2 = acc[jj][2] + bv, v3 = acc[jj][3] + bv;
            if (o >= 144) {
                v0 = 1.0f / (1.0f + expf(-v0));
                v1 = 1.0f / (1.0f + expf(-v1));
                v2 = 1.0f / (1.0f + expf(-v2));
                v3 = 1.0f / (1.0f + expf(-v3));
            }
            st = make_float4(v0, v1, v2, v3);
            *(float4*)&om[(size_t)(b * OMCH + o) * HWs + pos0 + pg * 4] = st;
        }
    }
}

// ---------------- DCNv2 + relu + residual ----------------
__global__ __launch_bounds__(256) void k_dcn(const float* __restrict__ fu,
                                             const float* __restrict__ om,
                                             const float* __restrict__ wrd,
                                             const float* __restrict__ bdcn,
                                             const float* __restrict__ fl,
                                             float* __restrict__ outp) {
    __shared__ float pw00[576], pw01[576], pw10[576], pw11[576];
    __shared__ int pidx[576];
    __shared__ float val_l[144][68];
    int t = threadIdx.x;
    int b = blockIdx.x >> 8;
    int pos0 = (blockIdx.x & 255) << 6;
    int y = pos0 >> 7, x0 = pos0 & 127;
    int og = t & 15, pg = t >> 4;
    float acc[8][4] = {};

    for (int g = 0; g < GG; ++g) {
        // phase 1: offsets/mask -> bilinear params
        for (int it = t; it < 576; it += 256) {
            int k = it >> 6, pos = it & 63;
            int x = x0 + pos;
            int ch0 = (g * 9 + k) * 2;
            size_t sp = (size_t)y * 128 + x;
            float oy = om[((size_t)(b * OMCH + ch0) * HWs) + sp];
            float ox = om[((size_t)(b * OMCH + ch0 + 1) * HWs) + sp];
            float m  = om[((size_t)(b * OMCH + 144 + g * 9 + k) * HWs) + sp];
            float py = (float)(y - 1 + (k / 3)) + oy;
            float px = (float)(x - 1 + (k % 3)) + ox;
            float fy0 = floorf(py), fx0 = floorf(px);
            float ly = py - fy0, lx = px - fx0;
            int y0 = (int)fy0, x0i = (int)fx0;
            int y1 = y0 + 1, x1 = x0i + 1;
            float vy0 = ((unsigned)y0 < 128u) ? 1.0f : 0.0f;
            float vy1 = ((unsigned)y1 < 128u) ? 1.0f : 0.0f;
            float vx0 = ((unsigned)x0i < 128u) ? 1.0f : 0.0f;
            float vx1 = ((unsigned)x1 < 128u) ? 1.0f : 0.0f;
            int yc0 = min(max(y0, 0), 127), yc1 = min(max(y1, 0), 127);
            int xc0 = min(max(x0i, 0), 127), xc1 = min(max(x1, 0), 127);
            pw00[it] = (1.0f - ly) * (1.0f - lx) * m * vy0 * vx0;
            pw01[it] = (1.0f - ly) * lx * m * vy0 * vx1;
            pw10[it] = ly * (1.0f - lx) * m * vy1 * vx0;
            pw11[it] = ly * lx * m * vy1 * vx1;
            pidx[it] = yc0 | (yc1 << 8) | (xc0 << 16) | (xc1 << 24);
        }
        __syncthreads();
        // phase 2: bilinear sampling -> val_l[c''*9+k][pos]
        {
            int w = t >> 6, posl = t & 63;
            const float* base0 = fu + (size_t)(b * 128 + g * 16) * HWs;
            for (int r = 0; r < 36; ++r) {
                int ck = r * 4 + w;           // c''*9 + k
                int k = ck % 9;
                int cch = ck / 9;
                int it = k * 64 + posl;
                int id = pidx[it];
                int yc0 = id & 255, yc1 = (id >> 8) & 255;
                int xc0 = (id >> 16) & 255, xc1 = (id >> 24) & 255;
                const float* bp = base0 + (size_t)cch * HWs;
                float v = pw00[it] * bp[yc0 * 128 + xc0]
                        + pw01[it] * bp[yc0 * 128 + xc1]
                        + pw10[it] * bp[yc1 * 128 + xc0]
                        + pw11[it] * bp[yc1 * 128 + xc1];
                val_l[ck][posl] = v;
            }
        }
        __syncthreads();
        // phase 3: GEMM accumulate over this group's 144 K
        #pragma unroll 4
        for (int i = 0; i < 144; ++i) {
            const float4 xv = *(const float4*)&val_l[i][pg * 4];
            const float* wr = wrd + (size_t)(g * 144 + i) * 128 + og * 8;
            const float4 wa = *(const float4*)wr;
            const float4 wb = *(const float4*)(wr + 4);
            float xs[4] = {xv.x, xv.y, xv.z, xv.w};
            float wv[8] = {wa.x, wa.y, wa.z, wa.w, wb.x, wb.y, wb.z, wb.w};
            #pragma unroll
            for (int jj = 0; jj < 8; ++jj)
                #pragma unroll
                for (int pp = 0; pp < 4; ++pp)
                    acc[jj][pp] = fmaf(wv[jj], xs[pp], acc[jj][pp]);
        }
        __syncthreads();
    }
    // epilogue: +bias, relu, +feat_l
    #pragma unroll
    for (int jj = 0; jj < 8; ++jj) {
        int o = og * 8 + jj;
        float bv = bdcn[o];
        size_t base = (size_t)(b * 128 + o) * HWs + pos0 + pg * 4;
        float4 res = *(const float4*)&fl[base];
        float4 st;
        st.x = fmaxf(acc[jj][0] + bv, 0.0f) + res.x;
        st.y = fmaxf(acc[jj][1] + bv, 0.0f) + res.y;
        st.z = fmaxf(acc[jj][2] + bv, 0.0f) + res.z;
        st.w = fmaxf(acc[jj][3] + bv, 0.0f) + res.w;
        *(float4*)&outp[base] = st;
    }
}

extern "C" void kernel_launch(void* const* d_in, const int* in_sizes, int n_in,
                              void* d_out, int out_size, void* d_ws, size_t ws_size,
                              hipStream_t stream) {
    const float* feat_l = (const float*)d_in[0];
    const float* feat_s = (const float*)d_in[1];
    const float* W_off  = (const float*)d_in[2];
    const float* W_om   = (const float*)d_in[3];
    const float* b_om   = (const float*)d_in[4];
    const float* W_dcn  = (const float*)d_in[5];
    const float* b_dcn  = (const float*)d_in[6];
    float* out = (float*)d_out;
    float* ws = (float*)d_ws;

    float* feat_up = ws;                     // 8,388,608
    float* offs    = ws + 8388608;           // 8,388,608
    float* om      = ws + 16777216;          // 14,155,776
    float* wt_off  = ws + 30932992;          // 32,768
    float* wr_om   = ws + 30965760;          // 294,912
    float* wr_dcn  = ws + 31260672;          // 147,456

    k_prep<<<1856, 256, 0, stream>>>(W_off, W_om, W_dcn, wt_off, wr_om, wr_dcn);
    k_upsample<<<32768, 256, 0, stream>>>(feat_s, feat_up);
    k_conv1<<<1024, 256, 0, stream>>>(feat_l, feat_up, wt_off, offs);
    k_conv3<<<dim3(1024, 2), 256, 0, stream>>>(offs, wr_om, b_om, om);
    k_dcn<<<1024, 256, 0, stream>>>(feat_up, om, wr_dcn, b_dcn, feat_l, out);
}

// Round 2
// 759.874 us; speedup vs baseline: 1.6565x; 1.6565x over previous
//
#include <hip/hip_runtime.h>
#include <hip/hip_bf16.h>
#include <math.h>

#define BB 4
#define CC 128
#define HH 128
#define WW 128
#define HWs 16384
#define GG 8
#define OMCH 216

typedef __bf16 bf16_t;
typedef bf16_t bf16x8 __attribute__((ext_vector_type(8)));
typedef float f32x4 __attribute__((ext_vector_type(4)));

// ---------------- prep: weight rearrange ----------------
// wt_off[c][o]            (256 x 128)  fp32
// wpack_om                 MFMA-fragment-packed bf16 W_om: [ks=cblk*9+tap][o_tile][lane][8]
// wr_dcn[(c*9+k)][o]      (1152 x 128) fp32
__global__ __launch_bounds__(256) void k_prep(const float* __restrict__ W_off,
                                              const float* __restrict__ W_om,
                                              const float* __restrict__ W_dcn,
                                              float* __restrict__ wt_off,
                                              bf16_t* __restrict__ wpack,
                                              float* __restrict__ wr_dcn) {
    int idx = blockIdx.x * 256 + threadIdx.x;
    if (idx < 32768) {
        int c = idx >> 7, o = idx & 127;
        wt_off[idx] = W_off[o * 256 + c];
    } else if (idx < 32768 + 36864) {
        int j = idx - 32768;
        int lane = j & 63;
        int rest = j >> 6;       // 0..575
        int ot = rest & 15;
        int ks = rest >> 4;      // 0..35
        int cblk = ks / 9, tap = ks % 9;
        int o = ot * 16 + (lane & 15);
        int cbase = cblk * 32 + ((lane >> 4) << 3);
        bf16x8 v;
        #pragma unroll
        for (int r = 0; r < 8; ++r) {
            float x = (o < OMCH) ? W_om[((o * 128 + cbase + r) * 9) + tap] : 0.0f;
            v[r] = (bf16_t)x;
        }
        *((bf16x8*)wpack + j) = v;
    } else if (idx < 32768 + 36864 + 147456) {
        int j = idx - 69632;
        int o = j & 127;
        int ck = j >> 7;            // c*9+k
        int c = ck / 9, k = ck % 9;
        wr_dcn[j] = W_dcn[(o * 128 + c) * 9 + k];
    }
}

// ---------------- bilinear 2x upsample ----------------
__global__ __launch_bounds__(256) void k_upsample(const float* __restrict__ fs,
                                                  float* __restrict__ fu) {
    int idx = blockIdx.x * 256 + threadIdx.x;   // over B*C*H*W (exact)
    int x = idx & 127, y = (idx >> 7) & 127, bc = idx >> 14;
    int j = y >> 1, i = x >> 1;
    int ya, yb; float wya, wyb;
    if (y & 1) { ya = j; yb = (j < 63) ? j + 1 : 63; wya = 0.75f; wyb = 0.25f; }
    else       { ya = (j > 0) ? j - 1 : 0; yb = j;   wya = 0.25f; wyb = 0.75f; }
    int xa, xb; float wxa, wxb;
    if (x & 1) { xa = i; xb = (i < 63) ? i + 1 : 63; wxa = 0.75f; wxb = 0.25f; }
    else       { xa = (i > 0) ? i - 1 : 0; xb = i;   wxa = 0.25f; wxb = 0.75f; }
    const float* p = fs + (size_t)bc * 4096;
    float v = wya * (wxa * p[ya * 64 + xa] + wxb * p[ya * 64 + xb])
            + wyb * (wxa * p[yb * 64 + xa] + wxb * p[yb * 64 + xb]);
    fu[idx] = v;
}

// ---------------- 1x1 conv: offset_feat = W_off * concat(feat_l, 2*feat_up) ----------------
#define XLD1 68
__global__ __launch_bounds__(256) void k_conv1(const float* __restrict__ fl,
                                               const float* __restrict__ fu,
                                               const float* __restrict__ wt,
                                               float* __restrict__ outp) {
    __shared__ float Xl[128][XLD1];
    int t = threadIdx.x;
    int b = blockIdx.x >> 8;
    int pos0 = (blockIdx.x & 255) << 6;
    int og = t & 15, pg = t >> 4;
    float acc[8][4] = {};
    for (int c0 = 0; c0 < 256; c0 += 128) {
        __syncthreads();
        int p = t & 63, cb = t >> 6;
        #pragma unroll
        for (int r = 0; r < 32; ++r) {
            int c = c0 + cb + r * 4;
            float v;
            if (c < 128) v = fl[(size_t)(b * 128 + c) * HWs + pos0 + p];
            else         v = 2.0f * fu[(size_t)(b * 128 + (c - 128)) * HWs + pos0 + p];
            Xl[cb + r * 4][p] = v;
        }
        __syncthreads();
        #pragma unroll 4
        for (int cc = 0; cc < 128; ++cc) {
            const float4 xv = *(const float4*)&Xl[cc][pg * 4];
            const float* wr = wt + (size_t)(c0 + cc) * 128 + og * 8;
            const float4 wa = *(const float4*)wr;
            const float4 wb = *(const float4*)(wr + 4);
            float xs[4] = {xv.x, xv.y, xv.z, xv.w};
            float wv[8] = {wa.x, wa.y, wa.z, wa.w, wb.x, wb.y, wb.z, wb.w};
            #pragma unroll
            for (int jj = 0; jj < 8; ++jj)
                #pragma unroll
                for (int pp = 0; pp < 4; ++pp)
                    acc[jj][pp] = fmaf(wv[jj], xs[pp], acc[jj][pp]);
        }
    }
    #pragma unroll
    for (int jj = 0; jj < 8; ++jj) {
        int o = og * 8 + jj;
        float4 st = make_float4(acc[jj][0], acc[jj][1], acc[jj][2], acc[jj][3]);
        *(float4*)&outp[(size_t)(b * 128 + o) * HWs + pos0 + pg * 4] = st;
    }
}

// ---------------- 3x3 conv via MFMA: om = conv(offset_feat, W_om) + b_om; sigmoid on ch>=144 ----
// Block: 64 positions x 256 output-channels (216 real). 4 waves: wave w owns
// o-tiles [4w..4w+3], p-tiles [0..3]. K = 9 taps x 128 ch, stepped as
// 4 channel-blocks(32) x 9 taps, one 16x16x32 MFMA per (o_tile,p_tile) per step.
#define X3LD 40   // channel dim padded 32->40 (80B row stride -> <=2-way bank alias)
__global__ __launch_bounds__(256) void k_conv3m(const float* __restrict__ A,
                                                const bf16_t* __restrict__ wpack,
                                                const float* __restrict__ bom,
                                                float* __restrict__ om) {
    __shared__ __align__(16) bf16_t Xs[3 * 66 * X3LD];
    int t = threadIdx.x;
    int lane = t & 63, w = t >> 6;
    int b = blockIdx.x >> 8;
    int pos0 = (blockIdx.x & 255) << 6;
    int y = pos0 >> 7, x0 = pos0 & 127;
    f32x4 acc[4][4];
    #pragma unroll
    for (int i = 0; i < 4; ++i)
        #pragma unroll
        for (int j = 0; j < 4; ++j)
            acc[i][j] = (f32x4){0.f, 0.f, 0.f, 0.f};

    for (int cblk = 0; cblk < 4; ++cblk) {
        __syncthreads();
        // stage 32 channels x 3 rows x 66 cols as bf16, layout [dy][col][ch]
        for (int id = t; id < 3168; id += 256) {
            int col = id % 66;
            int rest = id / 66;        // 0..47
            int dy = rest % 3;
            int cp = rest / 3;         // channel pair 0..15
            int gy = y - 1 + dy, gx = x0 - 1 + col;
            float v0 = 0.f, v1 = 0.f;
            if ((unsigned)gy < 128u && (unsigned)gx < 128u) {
                size_t gb = ((size_t)(b * 128 + cblk * 32 + cp * 2) * 128 + gy) * 128 + gx;
                v0 = A[gb];
                v1 = A[gb + HWs];
            }
            int le = (dy * 66 + col) * X3LD + cp * 2;
            Xs[le] = (bf16_t)v0;
            Xs[le + 1] = (bf16_t)v1;
        }
        __syncthreads();
        #pragma unroll
        for (int tap = 0; tap < 9; ++tap) {
            const int ky = tap / 3, kx = tap % 3;
            bf16x8 af[4], bf[4];
            const bf16x8* wp = (const bf16x8*)wpack + ((size_t)((cblk * 9 + tap) * 16 + w * 4) * 64 + lane);
            #pragma unroll
            for (int oi = 0; oi < 4; ++oi) af[oi] = wp[oi * 64];
            #pragma unroll
            for (int pi = 0; pi < 4; ++pi) {
                int colb = pi * 16 + (lane & 15) + kx;
                bf[pi] = *(const bf16x8*)&Xs[(ky * 66 + colb) * X3LD + ((lane >> 4) << 3)];
            }
            #pragma unroll
            for (int oi = 0; oi < 4; ++oi)
                #pragma unroll
                for (int pi = 0; pi < 4; ++pi)
                    acc[oi][pi] = __builtin_amdgcn_mfma_f32_16x16x32_bf16(af[oi], bf[pi], acc[oi][pi], 0, 0, 0);
        }
    }
    // epilogue: +bias, sigmoid on mask channels, fp32 store
    #pragma unroll
    for (int oi = 0; oi < 4; ++oi) {
        int obase = (w * 4 + oi) * 16 + ((lane >> 4) << 2);
        #pragma unroll
        for (int j = 0; j < 4; ++j) {
            int o = obase + j;
            if (o < OMCH) {
                float bv = bom[o];
                size_t ob = (size_t)(b * OMCH + o) * HWs + pos0 + (lane & 15);
                #pragma unroll
                for (int pi = 0; pi < 4; ++pi) {
                    float v = acc[oi][pi][j] + bv;
                    if (o >= 144) v = 1.0f / (1.0f + expf(-v));
                    om[ob + pi * 16] = v;
                }
            }
        }
    }
}

// ---------------- DCNv2 + relu + residual ----------------
__global__ __launch_bounds__(256) void k_dcn(const float* __restrict__ fu,
                                             const float* __restrict__ om,
                                             const float* __restrict__ wrd,
                                             const float* __restrict__ bdcn,
                                             const float* __restrict__ fl,
                                             float* __restrict__ outp) {
    __shared__ float pw00[576], pw01[576], pw10[576], pw11[576];
    __shared__ int pidx[576];
    __shared__ float val_l[144][68];
    int t = threadIdx.x;
    int b = blockIdx.x >> 8;
    int pos0 = (blockIdx.x & 255) << 6;
    int y = pos0 >> 7, x0 = pos0 & 127;
    int og = t & 15, pg = t >> 4;
    float acc[8][4] = {};

    for (int g = 0; g < GG; ++g) {
        // phase 1: offsets/mask -> bilinear params
        for (int it = t; it < 576; it += 256) {
            int k = it >> 6, pos = it & 63;
            int x = x0 + pos;
            int ch0 = (g * 9 + k) * 2;
            size_t sp = (size_t)y * 128 + x;
            float oy = om[((size_t)(b * OMCH + ch0) * HWs) + sp];
            float ox = om[((size_t)(b * OMCH + ch0 + 1) * HWs) + sp];
            float m  = om[((size_t)(b * OMCH + 144 + g * 9 + k) * HWs) + sp];
            float py = (float)(y - 1 + (k / 3)) + oy;
            float px = (float)(x - 1 + (k % 3)) + ox;
            float fy0 = floorf(py), fx0 = floorf(px);
            float ly = py - fy0, lx = px - fx0;
            int y0 = (int)fy0, x0i = (int)fx0;
            int y1 = y0 + 1, x1 = x0i + 1;
            float vy0 = ((unsigned)y0 < 128u) ? 1.0f : 0.0f;
            float vy1 = ((unsigned)y1 < 128u) ? 1.0f : 0.0f;
            float vx0 = ((unsigned)x0i < 128u) ? 1.0f : 0.0f;
            float vx1 = ((unsigned)x1 < 128u) ? 1.0f : 0.0f;
            int yc0 = min(max(y0, 0), 127), yc1 = min(max(y1, 0), 127);
            int xc0 = min(max(x0i, 0), 127), xc1 = min(max(x1, 0), 127);
            pw00[it] = (1.0f - ly) * (1.0f - lx) * m * vy0 * vx0;
            pw01[it] = (1.0f - ly) * lx * m * vy0 * vx1;
            pw10[it] = ly * (1.0f - lx) * m * vy1 * vx0;
            pw11[it] = ly * lx * m * vy1 * vx1;
            pidx[it] = yc0 | (yc1 << 8) | (xc0 << 16) | (xc1 << 24);
        }
        __syncthreads();
        // phase 2: bilinear sampling -> val_l[c''*9+k][pos]
        {
            int w = t >> 6, posl = t & 63;
            const float* base0 = fu + (size_t)(b * 128 + g * 16) * HWs;
            for (int r = 0; r < 36; ++r) {
                int ck = r * 4 + w;           // c''*9 + k
                int k = ck % 9;
                int cch = ck / 9;
                int it = k * 64 + posl;
                int id = pidx[it];
                int yc0 = id & 255, yc1 = (id >> 8) & 255;
                int xc0 = (id >> 16) & 255, xc1 = (id >> 24) & 255;
                const float* bp = base0 + (size_t)cch * HWs;
                float v = pw00[it] * bp[yc0 * 128 + xc0]
                        + pw01[it] * bp[yc0 * 128 + xc1]
                        + pw10[it] * bp[yc1 * 128 + xc0]
                        + pw11[it] * bp[yc1 * 128 + xc1];
                val_l[ck][posl] = v;
            }
        }
        __syncthreads();
        // phase 3: GEMM accumulate over this group's 144 K
        #pragma unroll 4
        for (int i = 0; i < 144; ++i) {
            const float4 xv = *(const float4*)&val_l[i][pg * 4];
            const float* wr = wrd + (size_t)(g * 144 + i) * 128 + og * 8;
            const float4 wa = *(const float4*)wr;
            const float4 wb = *(const float4*)(wr + 4);
            float xs[4] = {xv.x, xv.y, xv.z, xv.w};
            float wv[8] = {wa.x, wa.y, wa.z, wa.w, wb.x, wb.y, wb.z, wb.w};
            #pragma unroll
            for (int jj = 0; jj < 8; ++jj)
                #pragma unroll
                for (int pp = 0; pp < 4; ++pp)
                    acc[jj][pp] = fmaf(wv[jj], xs[pp], acc[jj][pp]);
        }
        __syncthreads();
    }
    // epilogue: +bias, relu, +feat_l
    #pragma unroll
    for (int jj = 0; jj < 8; ++jj) {
        int o = og * 8 + jj;
        float bv = bdcn[o];
        size_t base = (size_t)(b * 128 + o) * HWs + pos0 + pg * 4;
        float4 res = *(const float4*)&fl[base];
        float4 st;
        st.x = fmaxf(acc[jj][0] + bv, 0.0f) + res.x;
        st.y = fmaxf(acc[jj][1] + bv, 0.0f) + res.y;
        st.z = fmaxf(acc[jj][2] + bv, 0.0f) + res.z;
        st.w = fmaxf(acc[jj][3] + bv, 0.0f) + res.w;
        *(float4*)&outp[base] = st;
    }
}

extern "C" void kernel_launch(void* const* d_in, const int* in_sizes, int n_in,
                              void* d_out, int out_size, void* d_ws, size_t ws_size,
                              hipStream_t stream) {
    const float* feat_l = (const float*)d_in[0];
    const float* feat_s = (const float*)d_in[1];
    const float* W_off  = (const float*)d_in[2];
    const float* W_om   = (const float*)d_in[3];
    const float* b_om   = (const float*)d_in[4];
    const float* W_dcn  = (const float*)d_in[5];
    const float* b_dcn  = (const float*)d_in[6];
    float* out = (float*)d_out;
    float* ws = (float*)d_ws;

    float* feat_up = ws;                     // 8,388,608
    float* offs    = ws + 8388608;           // 8,388,608
    float* om      = ws + 16777216;          // 14,155,776
    float* wt_off  = ws + 30932992;          // 32,768
    float* wr_dcn  = ws + 30965760;          // 147,456
    bf16_t* wpack  = (bf16_t*)(ws + 31113216); // 294,912 bf16 = 147,456 floats

    k_prep<<<848, 256, 0, stream>>>(W_off, W_om, W_dcn, wt_off, wpack, wr_dcn);
    k_upsample<<<32768, 256, 0, stream>>>(feat_s, feat_up);
    k_conv1<<<1024, 256, 0, stream>>>(feat_l, feat_up, wt_off, offs);
    k_conv3m<<<1024, 256, 0, stream>>>(offs, wpack, b_om, om);
    k_dcn<<<1024, 256, 0, stream>>>(feat_up, om, wr_dcn, b_dcn, feat_l, out);
}

// Round 3
// 459.201 us; speedup vs baseline: 2.7412x; 1.6548x over previous
//
#include <hip/hip_runtime.h>
#include <hip/hip_bf16.h>
#include <math.h>

#define BB 4
#define CC 128
#define HH 128
#define WW 128
#define HWs 16384
#define GG 8
#define OMCH 216

typedef __bf16 bf16_t;
typedef bf16_t bf16x8 __attribute__((ext_vector_type(8)));
typedef float f32x4 __attribute__((ext_vector_type(4)));

// ---------------- prep: weight rearrange ----------------
// wt_off[c][o]   (256 x 128) fp32
// wpack_om       MFMA A-fragment-packed bf16 W_om: [ks=cblk*9+tap][o_tile][lane][8]
// wpack_dcn      MFMA A-fragment-packed bf16 W_dcn: [g][ks5][ot8][lane][8], K=ks*32+(lane>>4)*8+r,
//                K -> (tap = K>>4, c'' = K&15), zero for K>=144
__global__ __launch_bounds__(256) void k_prep(const float* __restrict__ W_off,
                                              const float* __restrict__ W_om,
                                              const float* __restrict__ W_dcn,
                                              float* __restrict__ wt_off,
                                              bf16_t* __restrict__ wpack,
                                              bf16_t* __restrict__ wpdcn) {
    int idx = blockIdx.x * 256 + threadIdx.x;
    if (idx < 32768) {
        int c = idx >> 7, o = idx & 127;
        wt_off[idx] = W_off[o * 256 + c];
    } else if (idx < 32768 + 36864) {
        int j = idx - 32768;
        int lane = j & 63;
        int rest = j >> 6;       // 0..575
        int ot = rest & 15;
        int ks = rest >> 4;      // 0..35
        int cblk = ks / 9, tap = ks % 9;
        int o = ot * 16 + (lane & 15);
        int cbase = cblk * 32 + ((lane >> 4) << 3);
        bf16x8 v;
        #pragma unroll
        for (int r = 0; r < 8; ++r) {
            float x = (o < OMCH) ? W_om[((o * 128 + cbase + r) * 9) + tap] : 0.0f;
            v[r] = (bf16_t)x;
        }
        *((bf16x8*)wpack + j) = v;
    } else if (idx < 32768 + 36864 + 20480) {
        int j = idx - 69632;
        int lane = j & 63;
        int rest = j >> 6;       // 0..319
        int ot = rest & 7;
        int gks = rest >> 3;     // 0..39
        int g = gks / 5, ks = gks % 5;
        int o = ot * 16 + (lane & 15);
        int Kbase = ks * 32 + ((lane >> 4) << 3);
        bf16x8 v;
        #pragma unroll
        for (int r = 0; r < 8; ++r) {
            int K = Kbase + r;
            float x = 0.0f;
            if (K < 144) {
                int tap = K >> 4, cpp = K & 15;
                x = W_dcn[((o * 128) + g * 16 + cpp) * 9 + tap];
            }
            v[r] = (bf16_t)x;
        }
        *((bf16x8*)wpdcn + j) = v;
    }
}

// ---------------- bilinear 2x upsample ----------------
__global__ __launch_bounds__(256) void k_upsample(const float* __restrict__ fs,
                                                  float* __restrict__ fu) {
    int idx = blockIdx.x * 256 + threadIdx.x;   // over B*C*H*W (exact)
    int x = idx & 127, y = (idx >> 7) & 127, bc = idx >> 14;
    int j = y >> 1, i = x >> 1;
    int ya, yb; float wya, wyb;
    if (y & 1) { ya = j; yb = (j < 63) ? j + 1 : 63; wya = 0.75f; wyb = 0.25f; }
    else       { ya = (j > 0) ? j - 1 : 0; yb = j;   wya = 0.25f; wyb = 0.75f; }
    int xa, xb; float wxa, wxb;
    if (x & 1) { xa = i; xb = (i < 63) ? i + 1 : 63; wxa = 0.75f; wxb = 0.25f; }
    else       { xa = (i > 0) ? i - 1 : 0; xb = i;   wxa = 0.25f; wxb = 0.75f; }
    const float* p = fs + (size_t)bc * 4096;
    float v = wya * (wxa * p[ya * 64 + xa] + wxb * p[ya * 64 + xb])
            + wyb * (wxa * p[yb * 64 + xa] + wxb * p[yb * 64 + xb]);
    fu[idx] = v;
}

// ---------------- 1x1 conv: offset_feat = W_off * concat(feat_l, 2*feat_up) ----------------
#define XLD1 68
__global__ __launch_bounds__(256) void k_conv1(const float* __restrict__ fl,
                                               const float* __restrict__ fu,
                                               const float* __restrict__ wt,
                                               float* __restrict__ outp) {
    __shared__ float Xl[128][XLD1];
    int t = threadIdx.x;
    int b = blockIdx.x >> 8;
    int pos0 = (blockIdx.x & 255) << 6;
    int og = t & 15, pg = t >> 4;
    float acc[8][4] = {};
    for (int c0 = 0; c0 < 256; c0 += 128) {
        __syncthreads();
        int p = t & 63, cb = t >> 6;
        #pragma unroll
        for (int r = 0; r < 32; ++r) {
            int c = c0 + cb + r * 4;
            float v;
            if (c < 128) v = fl[(size_t)(b * 128 + c) * HWs + pos0 + p];
            else         v = 2.0f * fu[(size_t)(b * 128 + (c - 128)) * HWs + pos0 + p];
            Xl[cb + r * 4][p] = v;
        }
        __syncthreads();
        #pragma unroll 4
        for (int cc = 0; cc < 128; ++cc) {
            const float4 xv = *(const float4*)&Xl[cc][pg * 4];
            const float* wr = wt + (size_t)(c0 + cc) * 128 + og * 8;
            const float4 wa = *(const float4*)wr;
            const float4 wb = *(const float4*)(wr + 4);
            float xs[4] = {xv.x, xv.y, xv.z, xv.w};
            float wv[8] = {wa.x, wa.y, wa.z, wa.w, wb.x, wb.y, wb.z, wb.w};
            #pragma unroll
            for (int jj = 0; jj < 8; ++jj)
                #pragma unroll
                for (int pp = 0; pp < 4; ++pp)
                    acc[jj][pp] = fmaf(wv[jj], xs[pp], acc[jj][pp]);
        }
    }
    #pragma unroll
    for (int jj = 0; jj < 8; ++jj) {
        int o = og * 8 + jj;
        float4 st = make_float4(acc[jj][0], acc[jj][1], acc[jj][2], acc[jj][3]);
        *(float4*)&outp[(size_t)(b * 128 + o) * HWs + pos0 + pg * 4] = st;
    }
}

// ---------------- 3x3 conv via MFMA ----------------
#define X3LD 40
__global__ __launch_bounds__(256) void k_conv3m(const float* __restrict__ A,
                                                const bf16_t* __restrict__ wpack,
                                                const float* __restrict__ bom,
                                                float* __restrict__ om) {
    __shared__ __align__(16) bf16_t Xs[3 * 66 * X3LD];
    int t = threadIdx.x;
    int lane = t & 63, w = t >> 6;
    int b = blockIdx.x >> 8;
    int pos0 = (blockIdx.x & 255) << 6;
    int y = pos0 >> 7, x0 = pos0 & 127;
    f32x4 acc[4][4];
    #pragma unroll
    for (int i = 0; i < 4; ++i)
        #pragma unroll
        for (int j = 0; j < 4; ++j)
            acc[i][j] = (f32x4){0.f, 0.f, 0.f, 0.f};

    for (int cblk = 0; cblk < 4; ++cblk) {
        __syncthreads();
        for (int id = t; id < 3168; id += 256) {
            int col = id % 66;
            int rest = id / 66;
            int dy = rest % 3;
            int cp = rest / 3;
            int gy = y - 1 + dy, gx = x0 - 1 + col;
            float v0 = 0.f, v1 = 0.f;
            if ((unsigned)gy < 128u && (unsigned)gx < 128u) {
                size_t gb = ((size_t)(b * 128 + cblk * 32 + cp * 2) * 128 + gy) * 128 + gx;
                v0 = A[gb];
                v1 = A[gb + HWs];
            }
            int le = (dy * 66 + col) * X3LD + cp * 2;
            Xs[le] = (bf16_t)v0;
            Xs[le + 1] = (bf16_t)v1;
        }
        __syncthreads();
        #pragma unroll
        for (int tap = 0; tap < 9; ++tap) {
            const int ky = tap / 3, kx = tap % 3;
            bf16x8 af[4], bfr[4];
            const bf16x8* wp = (const bf16x8*)wpack + ((size_t)((cblk * 9 + tap) * 16 + w * 4) * 64 + lane);
            #pragma unroll
            for (int oi = 0; oi < 4; ++oi) af[oi] = wp[oi * 64];
            #pragma unroll
            for (int pi = 0; pi < 4; ++pi) {
                int colb = pi * 16 + (lane & 15) + kx;
                bfr[pi] = *(const bf16x8*)&Xs[(ky * 66 + colb) * X3LD + ((lane >> 4) << 3)];
            }
            #pragma unroll
            for (int oi = 0; oi < 4; ++oi)
                #pragma unroll
                for (int pi = 0; pi < 4; ++pi)
                    acc[oi][pi] = __builtin_amdgcn_mfma_f32_16x16x32_bf16(af[oi], bfr[pi], acc[oi][pi], 0, 0, 0);
        }
    }
    #pragma unroll
    for (int oi = 0; oi < 4; ++oi) {
        int obase = (w * 4 + oi) * 16 + ((lane >> 4) << 2);
        #pragma unroll
        for (int j = 0; j < 4; ++j) {
            int o = obase + j;
            if (o < OMCH) {
                float bv = bom[o];
                size_t ob = (size_t)(b * OMCH + o) * HWs + pos0 + (lane & 15);
                #pragma unroll
                for (int pi = 0; pi < 4; ++pi) {
                    float v = acc[oi][pi][j] + bv;
                    if (o >= 144) v = 1.0f / (1.0f + expf(-v));
                    om[ob + pi * 16] = v;
                }
            }
        }
    }
}

// ---------------- DCNv2 via MFMA + relu + residual ----------------
// Block: 64 positions x 128 outputs. 4 waves; wave w owns o-tiles {2w,2w+1} x 4 p-tiles.
// Per group g: K=144 (tap*16+c'') padded to 160, 5 MFMA K-steps.
// val LDS: [pos 64][168 bf16] (stride 336B -> 2-way bank alias, free); cols 144..159 zeroed once.
__global__ __launch_bounds__(256) void k_dcn(const float* __restrict__ fu,
                                             const float* __restrict__ om,
                                             const bf16_t* __restrict__ wpd,
                                             const float* __restrict__ bdcn,
                                             const float* __restrict__ fl,
                                             float* __restrict__ outp) {
    __shared__ float pw00[576], pw01[576], pw10[576], pw11[576];
    __shared__ int pidx[576];
    __shared__ __align__(16) bf16_t val[64][168];
    int t = threadIdx.x;
    int lane = t & 63, w = t >> 6;
    int b = blockIdx.x >> 8;
    int pos0 = (blockIdx.x & 255) << 6;
    int y = pos0 >> 7, x0 = pos0 & 127;
    f32x4 acc[2][4];
    #pragma unroll
    for (int i = 0; i < 2; ++i)
        #pragma unroll
        for (int j = 0; j < 4; ++j)
            acc[i][j] = (f32x4){0.f, 0.f, 0.f, 0.f};
    // zero the K-pad columns once (never rewritten)
    for (int id = t; id < 64 * 24; id += 256)
        val[id / 24][144 + (id % 24)] = (bf16_t)0.0f;

    for (int g = 0; g < GG; ++g) {
        // phase 1: offsets/mask -> bilinear params
        for (int it = t; it < 576; it += 256) {
            int k = it >> 6, pos = it & 63;
            int x = x0 + pos;
            int ch0 = (g * 9 + k) * 2;
            size_t sp = (size_t)y * 128 + x;
            float oy = om[((size_t)(b * OMCH + ch0) * HWs) + sp];
            float ox = om[((size_t)(b * OMCH + ch0 + 1) * HWs) + sp];
            float m  = om[((size_t)(b * OMCH + 144 + g * 9 + k) * HWs) + sp];
            float py = (float)(y - 1 + (k / 3)) + oy;
            float px = (float)(x - 1 + (k % 3)) + ox;
            float fy0 = floorf(py), fx0 = floorf(px);
            float ly = py - fy0, lx = px - fx0;
            int y0 = (int)fy0, x0i = (int)fx0;
            int y1 = y0 + 1, x1 = x0i + 1;
            float vy0 = ((unsigned)y0 < 128u) ? 1.0f : 0.0f;
            float vy1 = ((unsigned)y1 < 128u) ? 1.0f : 0.0f;
            float vx0 = ((unsigned)x0i < 128u) ? 1.0f : 0.0f;
            float vx1 = ((unsigned)x1 < 128u) ? 1.0f : 0.0f;
            int yc0 = min(max(y0, 0), 127), yc1 = min(max(y1, 0), 127);
            int xc0 = min(max(x0i, 0), 127), xc1 = min(max(x1, 0), 127);
            pw00[it] = (1.0f - ly) * (1.0f - lx) * m * vy0 * vx0;
            pw01[it] = (1.0f - ly) * lx * m * vy0 * vx1;
            pw10[it] = ly * (1.0f - lx) * m * vy1 * vx0;
            pw11[it] = ly * lx * m * vy1 * vx1;
            pidx[it] = yc0 | (yc1 << 8) | (xc0 << 16) | (xc1 << 24);
        }
        __syncthreads();
        // phase 2: bilinear sampling -> val[pos][K=tap*16+c''] as bf16
        {
            int posl = t & 63;
            const float* base0 = fu + (size_t)(b * 128 + g * 16) * HWs;
            for (int r = 0; r < 36; ++r) {
                int ck2 = r * 4 + w;          // K index: tap*16 + c''
                int k = ck2 >> 4;
                int cch = ck2 & 15;
                int it = k * 64 + posl;
                int id = pidx[it];
                int yc0 = id & 255, yc1 = (id >> 8) & 255;
                int xc0 = (id >> 16) & 255, xc1 = (id >> 24) & 255;
                const float* bp = base0 + (size_t)cch * HWs;
                float v = pw00[it] * bp[yc0 * 128 + xc0]
                        + pw01[it] * bp[yc0 * 128 + xc1]
                        + pw10[it] * bp[yc1 * 128 + xc0]
                        + pw11[it] * bp[yc1 * 128 + xc1];
                val[posl][ck2] = (bf16_t)v;
            }
        }
        __syncthreads();
        // phase 3: MFMA accumulate, K=160 (5 steps)
        #pragma unroll
        for (int ks = 0; ks < 5; ++ks) {
            bf16x8 af[2], bfr[4];
            const bf16x8* wp = (const bf16x8*)wpd + (((g * 5 + ks) * 8 + w * 2) * 64 + lane);
            af[0] = wp[0];
            af[1] = wp[64];
            #pragma unroll
            for (int pi = 0; pi < 4; ++pi)
                bfr[pi] = *(const bf16x8*)&val[pi * 16 + (lane & 15)][ks * 32 + ((lane >> 4) << 3)];
            #pragma unroll
            for (int oi = 0; oi < 2; ++oi)
                #pragma unroll
                for (int pi = 0; pi < 4; ++pi)
                    acc[oi][pi] = __builtin_amdgcn_mfma_f32_16x16x32_bf16(af[oi], bfr[pi], acc[oi][pi], 0, 0, 0);
        }
        __syncthreads();
    }
    // epilogue: +bias, relu, +feat_l
    #pragma unroll
    for (int oi = 0; oi < 2; ++oi) {
        int obase = (w * 2 + oi) * 16 + ((lane >> 4) << 2);
        #pragma unroll
        for (int j = 0; j < 4; ++j) {
            int o = obase + j;
            float bv = bdcn[o];
            size_t base = (size_t)(b * 128 + o) * HWs + pos0 + (lane & 15);
            #pragma unroll
            for (int pi = 0; pi < 4; ++pi) {
                float v = fmaxf(acc[oi][pi][j] + bv, 0.0f) + fl[base + pi * 16];
                outp[base + pi * 16] = v;
            }
        }
    }
}

extern "C" void kernel_launch(void* const* d_in, const int* in_sizes, int n_in,
                              void* d_out, int out_size, void* d_ws, size_t ws_size,
                              hipStream_t stream) {
    const float* feat_l = (const float*)d_in[0];
    const float* feat_s = (const float*)d_in[1];
    const float* W_off  = (const float*)d_in[2];
    const float* W_om   = (const float*)d_in[3];
    const float* b_om   = (const float*)d_in[4];
    const float* W_dcn  = (const float*)d_in[5];
    const float* b_dcn  = (const float*)d_in[6];
    float* out = (float*)d_out;
    float* ws = (float*)d_ws;

    float* feat_up = ws;                       // 8,388,608 f
    float* offs    = ws + 8388608;             // 8,388,608 f
    float* om      = ws + 16777216;            // 14,155,776 f
    float* wt_off  = ws + 30932992;            // 32,768 f
    bf16_t* wpack  = (bf16_t*)(ws + 30965760); // 294,912 bf16 = 147,456 f
    bf16_t* wpdcn  = (bf16_t*)(ws + 31113216); // 163,840 bf16 = 81,920 f

    k_prep<<<352, 256, 0, stream>>>(W_off, W_om, W_dcn, wt_off, wpack, wpdcn);
    k_upsample<<<32768, 256, 0, stream>>>(feat_s, feat_up);
    k_conv1<<<1024, 256, 0, stream>>>(feat_l, feat_up, wt_off, offs);
    k_conv3m<<<1024, 256, 0, stream>>>(offs, wpack, b_om, om);
    k_dcn<<<1024, 256, 0, stream>>>(feat_up, om, wpdcn, b_dcn, feat_l, out);
}